// Round 6
// baseline (675.209 us; speedup 1.0000x reference)
//
#include <hip/hip_runtime.h>

// MSDNet on gfx950 — round 6: round-5 structure + 2-deep plane pipeline.
// R5 analysis: depth kernels are latency-exposed (VALUBusy 20%, occ 17%,
// VGPR=44 -> single tap buffer, vmcnt(0) each plane). Fix: double-buffer
// the 9 half8 taps across planes so plane c+1's loads are in flight while
// plane c's FMAs run (compiler emits fine-grained vmcnt). No other changes.
// ws: 30 zero-halo-padded fp16 planes (x,h0..h28) x 4 batches, HALO=16.
// Accumulation fp32, weights fp32. Depth 29 fuses 1x1 conv + output affine.

#define MSD_DEPTH 30
#define NB 4
#define IH 512
#define IW 512
#define HALO 16
#define WP (IW + 2 * HALO) /* 544 */
#define HP (IH + 2 * HALO) /* 544 */
#define PLANE ((size_t)WP * (size_t)HP) /* 295936 */
#define CSTRIDE ((size_t)NB * PLANE)
#define NPIX (NB * IH * IW) /* 1048576 */
#define NPLANES 30          /* planes 0..29 = x, h0..h28 */
#define GUARD ((size_t)(64 * WP))

typedef _Float16 h8 __attribute__((ext_vector_type(8)));   // 16B
typedef h8 h8u __attribute__((aligned(2)));
typedef float f4 __attribute__((ext_vector_type(4)));

__device__ __forceinline__ h8 ld8(const _Float16* p) { return *(const h8u*)p; }

// ---------------------------------------------------------------------------
__global__ __launch_bounds__(256) void zero_halo_kernel(_Float16* __restrict__ ws) {
    const int per = WP * HP - IW * IH; // 33792
    long idx = (long)blockIdx.x * 256 + threadIdx.x;
    const long total = (long)per * NPLANES * NB;
    if (idx >= total) return;
    int sub = (int)(idx / per);
    int rem = (int)(idx % per);
    int r, c;
    if (rem < HALO * WP) {
        r = rem / WP; c = rem % WP;
    } else if (rem < 2 * HALO * WP) {
        int t = rem - HALO * WP;
        r = (IH + HALO) + t / WP; c = t % WP;
    } else {
        int t = rem - 2 * HALO * WP;
        r = HALO + t / (2 * HALO);
        int u = t % (2 * HALO);
        c = (u < HALO) ? u : (IW + u);
    }
    ws[GUARD + (size_t)sub * PLANE + (size_t)r * WP + c] = (_Float16)0.f;
}

// ---------------------------------------------------------------------------
__global__ __launch_bounds__(256) void scale_in_kernel(const float* __restrict__ x,
                                                       _Float16* __restrict__ ws,
                                                       const float* __restrict__ sw,
                                                       const float* __restrict__ sb) {
    int s = blockIdx.x * 256 + threadIdx.x; // strip of 8 px
    int idx = s * 8;
    int w = idx & (IW - 1);
    int t = idx >> 9;
    int h = t & (IH - 1);
    int b = t >> 9;
    const float sws = sw[0], sbs = sb[0];
    h8 v;
#pragma unroll
    for (int j = 0; j < 8; ++j) v[j] = (_Float16)(x[idx + j] * sws + sbs);
    *(h8*)(ws + GUARD + (size_t)b * PLANE + (size_t)(h + HALO) * WP + (w + HALO)) = v;
}

// ---------------------------------------------------------------------------
template <int I>
__global__ __launch_bounds__(256) void depth_kernel(_Float16* __restrict__ ws,
                                                    const float* __restrict__ Wmsd,
                                                    const float* __restrict__ bias,
                                                    const float* __restrict__ convW,
                                                    const float* __restrict__ convB,
                                                    const float* __restrict__ soutw,
                                                    const float* __restrict__ soutb,
                                                    float* __restrict__ out) {
    constexpr int D = (I % 10) + 1;
    constexpr int NC = I + 1;
    constexpr bool LAST = (I == MSD_DEPTH - 1);

    const int tid = threadIdx.x;
    const int bid = blockIdx.x; // 512 blocks
    // XCD band swizzle (validated R4/R5): xcd = bid&7; 2 XCDs per image;
    // each XCD owns a contiguous 256-row band -> planes stay L2/LLC resident.
    const int xcd = bid & 7;
    const int k = bid >> 3;                  // 0..63
    const int b = xcd >> 1;                  // image
    const int ty = (xcd & 1) * 32 + (k >> 1);// 0..63 (8-px tile rows)
    const int tx = k & 1;                    // 0..1  (256-px tile cols)
    const int gx0 = tx * 256, gy0 = ty * 8;

    const int sx = (tid & 31) * 8;           // 32 strips per 256-px row
    const int sy = tid >> 5;                 // 8 rows
    const size_t ioff = (size_t)(gy0 + sy + HALO) * WP + (gx0 + sx + HALO);

    const _Float16* const P = ws + GUARD;
    const _Float16* pbase = P + (size_t)b * PLANE + ioff;

    float acc[8];
    float ydot[8];
#pragma unroll
    for (int j = 0; j < 8; ++j) { acc[j] = 0.f; ydot[j] = 0.f; }

    const float* wr = Wmsd + (size_t)I * (MSD_DEPTH * 9);

    h8 A[9], Bt[9];

#define LOAD9(dst, pp)                                                        \
    {                                                                         \
        const _Float16* p_ = (pp);                                            \
        dst[0] = ld8(p_ - D * WP - D); dst[1] = ld8(p_ - D * WP);             \
        dst[2] = ld8(p_ - D * WP + D); dst[3] = ld8(p_ - D);                  \
        dst[4] = ld8(p_);              dst[5] = ld8(p_ + D);                  \
        dst[6] = ld8(p_ + D * WP - D); dst[7] = ld8(p_ + D * WP);             \
        dst[8] = ld8(p_ + D * WP + D);                                        \
    }

    auto compute = [&](const h8* t, int c) {
        const float* wk = wr + c * 9;
        const float w0 = wk[0], w1 = wk[1], w2 = wk[2], w3 = wk[3], w4 = wk[4],
                    w5 = wk[5], w6 = wk[6], w7 = wk[7], w8 = wk[8];
        const float cw = LAST ? convW[c] : 0.f;
#pragma unroll
        for (int j = 0; j < 8; ++j) {
            float s = acc[j];
            s += w0 * (float)t[0][j]; s += w1 * (float)t[1][j]; s += w2 * (float)t[2][j];
            s += w3 * (float)t[3][j]; s += w4 * (float)t[4][j]; s += w5 * (float)t[5][j];
            s += w6 * (float)t[6][j]; s += w7 * (float)t[7][j]; s += w8 * (float)t[8][j];
            acc[j] = s;
            if (LAST) ydot[j] += cw * (float)t[4][j];
        }
    };

    // 2-deep software pipeline over planes: while computing plane c, plane
    // c+1's 9 loads are in flight (fine-grained vmcnt instead of vmcnt(0)).
    LOAD9(A, pbase);
    int c = 0;
    for (; c + 2 <= NC; c += 2) {
        LOAD9(Bt, pbase + (size_t)(c + 1) * CSTRIDE);
        compute(A, c);
        if (c + 2 < NC) LOAD9(A, pbase + (size_t)(c + 2) * CSTRIDE);
        compute(Bt, c + 1);
    }
    if (c < NC) compute(A, c); // odd-NC tail (A holds plane NC-1)
#undef LOAD9

    const float b0 = bias[I];
    if (!LAST) {
        _Float16* q = ws + GUARD + (size_t)(NC * NB + b) * PLANE + ioff;
        h8 hv;
#pragma unroll
        for (int j = 0; j < 8; ++j) {
            float h = acc[j] + b0;
            hv[j] = (_Float16)(h > 0.f ? h : 0.f);
        }
        *(h8*)q = hv;
    } else {
        const float cw29 = convW[MSD_DEPTH];
        const float cb = convB[0], ow = soutw[0], ob = soutb[0];
        float* q = out + ((size_t)(b * IH) + gy0 + sy) * IW + gx0 + sx;
        f4 y0, y1;
#pragma unroll
        for (int j = 0; j < 8; ++j) {
            float h = acc[j] + b0;
            h = h > 0.f ? h : 0.f;
            float y = ydot[j] + cw29 * h + cb;
            y = y * ow + ob;
            if (j < 4) y0[j] = y; else y1[j - 4] = y;
        }
        *(f4*)q = y0;
        *(f4*)(q + 4) = y1;
    }
}

// ---------------------------------------------------------------------------
extern "C" void kernel_launch(void* const* d_in, const int* in_sizes, int n_in,
                              void* d_out, int out_size, void* d_ws, size_t ws_size,
                              hipStream_t stream) {
    const float* x     = (const float*)d_in[0];
    const float* Wmsd  = (const float*)d_in[1];
    const float* bias  = (const float*)d_in[2];
    const float* convW = (const float*)d_in[3];
    const float* convB = (const float*)d_in[4];
    const float* sinw  = (const float*)d_in[5];
    const float* sinb  = (const float*)d_in[6];
    const float* soutw = (const float*)d_in[7];
    const float* soutb = (const float*)d_in[8];
    float* out = (float*)d_out;
    _Float16* ws = (_Float16*)d_ws;

    const long halo_total = (long)(WP * HP - IW * IH) * NPLANES * NB;
    int zb = (int)((halo_total + 255) / 256);
    zero_halo_kernel<<<zb, 256, 0, stream>>>(ws);

    scale_in_kernel<<<NPIX / 8 / 256, 256, 0, stream>>>(x, ws, sinw, sinb);

#define LNCH(I) depth_kernel<I><<<512, 256, 0, stream>>>(ws, Wmsd, bias, convW, convB, soutw, soutb, out);
    LNCH(0)  LNCH(1)  LNCH(2)  LNCH(3)  LNCH(4)
    LNCH(5)  LNCH(6)  LNCH(7)  LNCH(8)  LNCH(9)
    LNCH(10) LNCH(11) LNCH(12) LNCH(13) LNCH(14)
    LNCH(15) LNCH(16) LNCH(17) LNCH(18) LNCH(19)
    LNCH(20) LNCH(21) LNCH(22) LNCH(23) LNCH(24)
    LNCH(25) LNCH(26) LNCH(27) LNCH(28) LNCH(29)
#undef LNCH
}